// Round 1
// baseline (604.612 us; speedup 1.0000x reference)
//
#include <hip/hip_runtime.h>

typedef __bf16 bf16;
typedef __bf16 bf16x8 __attribute__((ext_vector_type(8)));
typedef __bf16 bf16x4 __attribute__((ext_vector_type(4)));
typedef float f32x4 __attribute__((ext_vector_type(4)));

// async global->LDS, 16B per lane; LDS dest is wave-uniform base + lane*16
__device__ __forceinline__ void gl_lds16(const bf16* g, bf16* l) {
  __builtin_amdgcn_global_load_lds(
      (__attribute__((address_space(1))) void*)g,
      (__attribute__((address_space(3))) void*)l, 16, 0, 0);
}

// ---------------- fp32 -> bf16 convert, 8 elems/thread ----------------
__global__ __launch_bounds__(256) void cvt_f32_bf16(
    const float* __restrict__ src, bf16* __restrict__ dst, int n8) {
  int i = blockIdx.x * 256 + threadIdx.x;
  if (i >= n8) return;
  const float4* s4 = (const float4*)src;
  float4 a = s4[2 * i], b = s4[2 * i + 1];
  bf16x8 o = {(bf16)a.x, (bf16)a.y, (bf16)a.z, (bf16)a.w,
              (bf16)b.x, (bf16)b.y, (bf16)b.z, (bf16)b.w};
  *(bf16x8*)(dst + (size_t)i * 8) = o;
}

// ------- V [2048,1024] f32 -> VT [1024,2048] bf16, per batch ----------
__global__ __launch_bounds__(256) void transpose_v(
    const float* __restrict__ V, bf16* __restrict__ VT) {
  int b = blockIdx.z;
  const float* Vb = V + (size_t)b * 2048 * 1024;
  bf16* Tb = VT + (size_t)b * 1024 * 2048;
  __shared__ float tile[32][33];  // +1 pad: conflict-free transposed read
  int tx = threadIdx.x, ty = threadIdx.y;
  int x = blockIdx.x * 32 + tx;
  int yb = blockIdx.y * 32;
#pragma unroll
  for (int j = 0; j < 4; j++)
    tile[ty + j * 8][tx] = Vb[(size_t)(yb + ty + j * 8) * 1024 + x];
  __syncthreads();
  int xo = yb + tx;
#pragma unroll
  for (int j = 0; j < 4; j++)
    Tb[(size_t)(blockIdx.x * 32 + ty + j * 8) * 2048 + xo] =
        (bf16)tile[tx][ty + j * 8];
}

// ---------------- shared B^T MFMA GEMM: C = A[M,K] * Bm[N,K]^T --------
// MODE 0: C bf16 = acc + bias[col]          (projection)
// MODE 1: C f32  = mask[col] ? acc/32 : -1e9 (QK^T scores)
// MODE 2: C f32  = acc                       (PV output)
template <int MODE>
__global__ __launch_bounds__(256) void gemm_bt(
    const bf16* __restrict__ A, const bf16* __restrict__ Bm,
    void* __restrict__ Cv, const float* __restrict__ bias,
    const int* __restrict__ mask, int M, int N, int K,
    long long sA, long long sB, long long sC) {
  const int b = blockIdx.z;
  const bf16* Ab = A + (long long)b * sA;
  const bf16* Bb = Bm + (long long)b * sB;
  const int m0 = blockIdx.y * 128, n0 = blockIdx.x * 128;
  __shared__ __align__(16) bf16 lA[128 * 64];
  __shared__ __align__(16) bf16 lB[128 * 64];
  const int tid = threadIdx.x, w = tid >> 6, lane = tid & 63;
  const int wm = (w >> 1) * 64, wn = (w & 1) * 64;  // 2x2 wave grid, 64x64/wave
  const int lrow = lane >> 3, lcol = (lane & 7) * 8;

  f32x4 zero = {0.f, 0.f, 0.f, 0.f};
  f32x4 acc[4][4];
#pragma unroll
  for (int i = 0; i < 4; i++)
#pragma unroll
    for (int j = 0; j < 4; j++) acc[i][j] = zero;

  const bf16* Aq = Ab + (long long)m0 * K;
  const bf16* Bq = Bb + (long long)n0 * K;
  const int fr = lane & 15, fq = (lane >> 4) * 8;  // MFMA A/B frag coords

  for (int ks = 0; ks < K; ks += 64) {
    // stage 128x64 bf16 tiles of A and B; 8 rows (1 KiB) per wave-instr
#pragma unroll
    for (int i = 0; i < 4; i++) {
      int t = w * 4 + i;
      int r = t * 8 + lrow;
      gl_lds16(Aq + (long long)r * K + (ks + lcol), &lA[t * 512]);
      gl_lds16(Bq + (long long)r * K + (ks + lcol), &lB[t * 512]);
    }
    __syncthreads();  // implies s_waitcnt vmcnt(0): LDS writes visible
#pragma unroll
    for (int kc = 0; kc < 2; kc++) {
      bf16x8 af[4], bfr[4];
#pragma unroll
      for (int mi = 0; mi < 4; mi++)
        af[mi] = *(const bf16x8*)&lA[(wm + mi * 16 + fr) * 64 + kc * 32 + fq];
#pragma unroll
      for (int ni = 0; ni < 4; ni++)
        bfr[ni] = *(const bf16x8*)&lB[(wn + ni * 16 + fr) * 64 + kc * 32 + fq];
#pragma unroll
      for (int mi = 0; mi < 4; mi++)
#pragma unroll
        for (int ni = 0; ni < 4; ni++)
          acc[mi][ni] = __builtin_amdgcn_mfma_f32_16x16x32_bf16(
              af[mi], bfr[ni], acc[mi][ni], 0, 0, 0);
    }
    __syncthreads();
  }

  // C/D layout (m89/m91-verified): row=(lane>>4)*4+reg, col=lane&15
  const int erow = (lane >> 4) * 4, ecol = lane & 15;
  if constexpr (MODE == 0) {
    bf16* C = (bf16*)Cv;
#pragma unroll
    for (int mi = 0; mi < 4; mi++)
#pragma unroll
      for (int r = 0; r < 4; r++) {
        int row = m0 + wm + mi * 16 + erow + r;
#pragma unroll
        for (int ni = 0; ni < 4; ni++) {
          int col = n0 + wn + ni * 16 + ecol;
          C[(long long)row * N + col] = (bf16)(acc[mi][ni][r] + bias[col]);
        }
      }
  } else if constexpr (MODE == 1) {
    float* C = (float*)Cv + (long long)b * sC;
    const int* mb = mask + b * 2048;
#pragma unroll
    for (int ni = 0; ni < 4; ni++) {
      int col = n0 + wn + ni * 16 + ecol;
      bool keep = mb[col] != 0;
#pragma unroll
      for (int mi = 0; mi < 4; mi++)
#pragma unroll
        for (int r = 0; r < 4; r++) {
          int row = m0 + wm + mi * 16 + erow + r;
          C[(long long)row * N + col] = keep ? acc[mi][ni][r] * 0.03125f : -1e9f;
        }
    }
  } else {
    float* C = (float*)Cv + (long long)b * sC;
#pragma unroll
    for (int mi = 0; mi < 4; mi++)
#pragma unroll
      for (int r = 0; r < 4; r++) {
        int row = m0 + wm + mi * 16 + erow + r;
#pragma unroll
        for (int ni = 0; ni < 4; ni++) {
          int col = n0 + wn + ni * 16 + ecol;
          C[(long long)row * N + col] = acc[mi][ni][r];
        }
      }
  }
}

// ---------------- row softmax: S f32 [.,2048] -> P bf16 ----------------
__global__ __launch_bounds__(256) void softmax_rows(
    const float* __restrict__ S, bf16* __restrict__ P) {
  long long row = blockIdx.x;
  const float4* src = (const float4*)(S + row * 2048);
  int tid = threadIdx.x, w = tid >> 6, lane = tid & 63;
  float4 v0 = src[tid], v1 = src[tid + 256];
  float m = fmaxf(fmaxf(fmaxf(v0.x, v0.y), fmaxf(v0.z, v0.w)),
                  fmaxf(fmaxf(v1.x, v1.y), fmaxf(v1.z, v1.w)));
#pragma unroll
  for (int off = 32; off; off >>= 1) m = fmaxf(m, __shfl_xor(m, off, 64));
  __shared__ float redm[4], reds[4];
  if (lane == 0) redm[w] = m;
  __syncthreads();
  m = fmaxf(fmaxf(redm[0], redm[1]), fmaxf(redm[2], redm[3]));
  float e[8];
  e[0] = __expf(v0.x - m); e[1] = __expf(v0.y - m);
  e[2] = __expf(v0.z - m); e[3] = __expf(v0.w - m);
  e[4] = __expf(v1.x - m); e[5] = __expf(v1.y - m);
  e[6] = __expf(v1.z - m); e[7] = __expf(v1.w - m);
  float s = e[0] + e[1] + e[2] + e[3] + e[4] + e[5] + e[6] + e[7];
#pragma unroll
  for (int off = 32; off; off >>= 1) s += __shfl_xor(s, off, 64);
  if (lane == 0) reds[w] = s;
  __syncthreads();
  s = reds[0] + reds[1] + reds[2] + reds[3];
  float inv = 1.0f / s;
  bf16x4 o0 = {(bf16)(e[0] * inv), (bf16)(e[1] * inv),
               (bf16)(e[2] * inv), (bf16)(e[3] * inv)};
  bf16x4 o1 = {(bf16)(e[4] * inv), (bf16)(e[5] * inv),
               (bf16)(e[6] * inv), (bf16)(e[7] * inv)};
  bf16* Pr = P + row * 2048;
  *(bf16x4*)(Pr + tid * 4) = o0;
  *(bf16x4*)(Pr + 1024 + tid * 4) = o1;
}

extern "C" void kernel_launch(void* const* d_in, const int* in_sizes, int n_in,
                              void* d_out, int out_size, void* d_ws,
                              size_t ws_size, hipStream_t stream) {
  const float* query = (const float*)d_in[0];
  const float* key_in = (const float*)d_in[1];
  const float* value = (const float*)d_in[2];
  const int* mask = (const int*)d_in[3];
  const float* Wq_w = (const float*)d_in[4];
  const float* Wq_b = (const float*)d_in[5];
  const float* Wk_w = (const float*)d_in[6];
  const float* Wk_b = (const float*)d_in[7];
  float* out = (float*)d_out;

  // workspace layout (224 MB), regions time-shared:
  //  [0,128MB):  qx(32) kx(32) wq(2) wk(2)  -> then S f32 (128)
  //  [128,192MB): qp(32) kp(32)             -> then P bf16 (64)
  //  [192,224MB): vt bf16 (32)
  const size_t MB = 1ull << 20;
  char* base = (char*)d_ws;
  bf16* qx = (bf16*)(base + 0 * MB);
  bf16* kx = (bf16*)(base + 32 * MB);
  bf16* wq = (bf16*)(base + 64 * MB);
  bf16* wk = (bf16*)(base + 66 * MB);
  float* S = (float*)(base + 0 * MB);
  bf16* qp = (bf16*)(base + 128 * MB);
  bf16* kp = (bf16*)(base + 160 * MB);
  bf16* P = (bf16*)(base + 128 * MB);
  bf16* vt = (bf16*)(base + 192 * MB);

  cvt_f32_bf16<<<8192, 256, 0, stream>>>(query, qx, 2097152);
  cvt_f32_bf16<<<8192, 256, 0, stream>>>(key_in, kx, 2097152);
  cvt_f32_bf16<<<512, 256, 0, stream>>>(Wq_w, wq, 131072);
  cvt_f32_bf16<<<512, 256, 0, stream>>>(Wk_w, wk, 131072);
  transpose_v<<<dim3(32, 64, 8), dim3(32, 8), 0, stream>>>(value, vt);

  // projections: q = query @ Wq^T + b, k = key @ Wk^T + b   (bf16 out)
  gemm_bt<0><<<dim3(8, 128, 1), 256, 0, stream>>>(
      qx, wq, qp, Wq_b, nullptr, 16384, 1024, 1024, 0, 0, 0);
  gemm_bt<0><<<dim3(8, 128, 1), 256, 0, stream>>>(
      kx, wk, kp, Wk_b, nullptr, 16384, 1024, 1024, 0, 0, 0);
  // scores: S = mask ? (q @ k^T)/32 : -1e9   (f32 out, batched)
  gemm_bt<1><<<dim3(16, 16, 8), 256, 0, stream>>>(
      qp, kp, S, nullptr, mask, 2048, 2048, 1024, 2048LL * 1024,
      2048LL * 1024, 2048LL * 2048);
  softmax_rows<<<16384, 256, 0, stream>>>(S, P);
  // out = P @ V  (via V^T, f32 out, batched)
  gemm_bt<2><<<dim3(8, 16, 8), 256, 0, stream>>>(
      P, vt, out, nullptr, nullptr, 2048, 1024, 2048, 2048LL * 2048,
      1024LL * 2048, 2048LL * 1024);
}

// Round 2
// 584.300 us; speedup vs baseline: 1.0348x; 1.0348x over previous
//
#include <hip/hip_runtime.h>

typedef __bf16 bf16;
typedef __bf16 bf16x8 __attribute__((ext_vector_type(8)));
typedef __bf16 bf16x4 __attribute__((ext_vector_type(4)));
typedef float f32x4 __attribute__((ext_vector_type(4)));

// async global->LDS, 16B per lane; LDS dest is wave-uniform base + lane*16
__device__ __forceinline__ void gl_lds16(const bf16* g, bf16* l) {
  __builtin_amdgcn_global_load_lds(
      (__attribute__((address_space(1))) void*)g,
      (__attribute__((address_space(3))) void*)l, 16, 0, 0);
}

// ---------------- fp32 -> bf16 convert, 8 elems/thread ----------------
__global__ __launch_bounds__(256) void cvt_f32_bf16(
    const float* __restrict__ src, bf16* __restrict__ dst, int n8) {
  int i = blockIdx.x * 256 + threadIdx.x;
  if (i >= n8) return;
  const float4* s4 = (const float4*)src;
  float4 a = s4[2 * i], b = s4[2 * i + 1];
  bf16x8 o = {(bf16)a.x, (bf16)a.y, (bf16)a.z, (bf16)a.w,
              (bf16)b.x, (bf16)b.y, (bf16)b.z, (bf16)b.w};
  *(bf16x8*)(dst + (size_t)i * 8) = o;
}

// ------- V [2048,1024] f32 -> VT [1024,2048] bf16, per batch ----------
__global__ __launch_bounds__(256) void transpose_v(
    const float* __restrict__ V, bf16* __restrict__ VT) {
  int b = blockIdx.z;
  const float* Vb = V + (size_t)b * 2048 * 1024;
  bf16* Tb = VT + (size_t)b * 1024 * 2048;
  __shared__ float tile[32][33];  // +1 pad: conflict-free transposed read
  int tx = threadIdx.x, ty = threadIdx.y;
  int x = blockIdx.x * 32 + tx;
  int yb = blockIdx.y * 32;
#pragma unroll
  for (int j = 0; j < 4; j++)
    tile[ty + j * 8][tx] = Vb[(size_t)(yb + ty + j * 8) * 1024 + x];
  __syncthreads();
  int xo = yb + tx;
#pragma unroll
  for (int j = 0; j < 4; j++)
    Tb[(size_t)(blockIdx.x * 32 + ty + j * 8) * 2048 + xo] =
        (bf16)tile[tx][ty + j * 8];
}

// ---------------- shared B^T MFMA GEMM: C = A[M,K] * Bm[N,K]^T --------
// LDS layout is XOR-swizzled: row r's 16B granule g lives at slot g^(r&7).
// Staging achieves this by permuting the GLOBAL granule each lane fetches
// (same 128B row -> same cache lines -> same coalescing); reads XOR back.
// This spreads each quarter-wave's fragment reads over all 32 banks
// (was: 16 lanes on one 4-bank granule = 16-way conflict, 2.5e7
// SQ_LDS_BANK_CONFLICT per dispatch).
// MODE 0: C bf16 = acc + bias[col]          (projection)
// MODE 1: C f32  = mask[col] ? acc/32 : -1e9 (QK^T scores)
// MODE 2: C f32  = acc                       (PV output)
template <int MODE>
__global__ __launch_bounds__(256) void gemm_bt(
    const bf16* __restrict__ A, const bf16* __restrict__ Bm,
    void* __restrict__ Cv, const float* __restrict__ bias,
    const int* __restrict__ mask, int M, int N, int K,
    long long sA, long long sB, long long sC) {
  const int b = blockIdx.z;
  const bf16* Ab = A + (long long)b * sA;
  const bf16* Bb = Bm + (long long)b * sB;
  const int m0 = blockIdx.y * 128, n0 = blockIdx.x * 128;
  __shared__ __align__(16) bf16 lA[128 * 64];
  __shared__ __align__(16) bf16 lB[128 * 64];
  const int tid = threadIdx.x, w = tid >> 6, lane = tid & 63;
  const int wm = (w >> 1) * 64, wn = (w & 1) * 64;  // 2x2 wave grid, 64x64/wave
  const int lrow = lane >> 3;                       // staging row within 8-row chunk
  const int gsw = (((lane & 7) ^ lrow) * 8);        // swizzled global granule (bf16 units)

  f32x4 zero = {0.f, 0.f, 0.f, 0.f};
  f32x4 acc[4][4];
#pragma unroll
  for (int i = 0; i < 4; i++)
#pragma unroll
    for (int j = 0; j < 4; j++) acc[i][j] = zero;

  const bf16* Aq = Ab + (long long)m0 * K;
  const bf16* Bq = Bb + (long long)n0 * K;
  const int fr = lane & 15;        // MFMA frag row
  const int fg = lane >> 4;        // logical granule within half-row (0..3)
  const int frx = fr & 7;          // swizzle key

  for (int ks = 0; ks < K; ks += 64) {
    // stage 128x64 bf16 tiles of A and B; 8 rows (1 KiB) per wave-instr
#pragma unroll
    for (int i = 0; i < 4; i++) {
      int t = w * 4 + i;
      int r = t * 8 + lrow;
      gl_lds16(Aq + (long long)r * K + (ks + gsw), &lA[t * 512]);
      gl_lds16(Bq + (long long)r * K + (ks + gsw), &lB[t * 512]);
    }
    __syncthreads();  // implies s_waitcnt vmcnt(0): LDS writes visible
#pragma unroll
    for (int kc = 0; kc < 2; kc++) {
      const int col = ((kc * 4 + fg) ^ frx) * 8;  // swizzled granule offset
      bf16x8 af[4], bfr[4];
#pragma unroll
      for (int mi = 0; mi < 4; mi++)
        af[mi] = *(const bf16x8*)&lA[(wm + mi * 16 + fr) * 64 + col];
#pragma unroll
      for (int ni = 0; ni < 4; ni++)
        bfr[ni] = *(const bf16x8*)&lB[(wn + ni * 16 + fr) * 64 + col];
#pragma unroll
      for (int mi = 0; mi < 4; mi++)
#pragma unroll
        for (int ni = 0; ni < 4; ni++)
          acc[mi][ni] = __builtin_amdgcn_mfma_f32_16x16x32_bf16(
              af[mi], bfr[ni], acc[mi][ni], 0, 0, 0);
    }
    __syncthreads();
  }

  // C/D layout (m89/m91-verified): row=(lane>>4)*4+reg, col=lane&15
  const int erow = (lane >> 4) * 4, ecol = lane & 15;
  if constexpr (MODE == 0) {
    bf16* C = (bf16*)Cv;
#pragma unroll
    for (int mi = 0; mi < 4; mi++)
#pragma unroll
      for (int r = 0; r < 4; r++) {
        int row = m0 + wm + mi * 16 + erow + r;
#pragma unroll
        for (int ni = 0; ni < 4; ni++) {
          int col = n0 + wn + ni * 16 + ecol;
          C[(long long)row * N + col] = (bf16)(acc[mi][ni][r] + bias[col]);
        }
      }
  } else if constexpr (MODE == 1) {
    float* C = (float*)Cv + (long long)b * sC;
    const int* mb = mask + b * 2048;
#pragma unroll
    for (int ni = 0; ni < 4; ni++) {
      int col = n0 + wn + ni * 16 + ecol;
      bool keep = mb[col] != 0;
#pragma unroll
      for (int mi = 0; mi < 4; mi++)
#pragma unroll
        for (int r = 0; r < 4; r++) {
          int row = m0 + wm + mi * 16 + erow + r;
          C[(long long)row * N + col] = keep ? acc[mi][ni][r] * 0.03125f : -1e9f;
        }
    }
  } else {
    float* C = (float*)Cv + (long long)b * sC;
#pragma unroll
    for (int mi = 0; mi < 4; mi++)
#pragma unroll
      for (int r = 0; r < 4; r++) {
        int row = m0 + wm + mi * 16 + erow + r;
#pragma unroll
        for (int ni = 0; ni < 4; ni++) {
          int col = n0 + wn + ni * 16 + ecol;
          C[(long long)row * N + col] = acc[mi][ni][r];
        }
      }
  }
}

// ---------------- row softmax: S f32 [.,2048] -> P bf16 ----------------
__global__ __launch_bounds__(256) void softmax_rows(
    const float* __restrict__ S, bf16* __restrict__ P) {
  long long row = blockIdx.x;
  const float4* src = (const float4*)(S + row * 2048);
  int tid = threadIdx.x, w = tid >> 6, lane = tid & 63;
  float4 v0 = src[tid], v1 = src[tid + 256];
  float m = fmaxf(fmaxf(fmaxf(v0.x, v0.y), fmaxf(v0.z, v0.w)),
                  fmaxf(fmaxf(v1.x, v1.y), fmaxf(v1.z, v1.w)));
#pragma unroll
  for (int off = 32; off; off >>= 1) m = fmaxf(m, __shfl_xor(m, off, 64));
  __shared__ float redm[4], reds[4];
  if (lane == 0) redm[w] = m;
  __syncthreads();
  m = fmaxf(fmaxf(redm[0], redm[1]), fmaxf(redm[2], redm[3]));
  float e[8];
  e[0] = __expf(v0.x - m); e[1] = __expf(v0.y - m);
  e[2] = __expf(v0.z - m); e[3] = __expf(v0.w - m);
  e[4] = __expf(v1.x - m); e[5] = __expf(v1.y - m);
  e[6] = __expf(v1.z - m); e[7] = __expf(v1.w - m);
  float s = e[0] + e[1] + e[2] + e[3] + e[4] + e[5] + e[6] + e[7];
#pragma unroll
  for (int off = 32; off; off >>= 1) s += __shfl_xor(s, off, 64);
  if (lane == 0) reds[w] = s;
  __syncthreads();
  s = reds[0] + reds[1] + reds[2] + reds[3];
  float inv = 1.0f / s;
  bf16x4 o0 = {(bf16)(e[0] * inv), (bf16)(e[1] * inv),
               (bf16)(e[2] * inv), (bf16)(e[3] * inv)};
  bf16x4 o1 = {(bf16)(e[4] * inv), (bf16)(e[5] * inv),
               (bf16)(e[6] * inv), (bf16)(e[7] * inv)};
  bf16* Pr = P + row * 2048;
  *(bf16x4*)(Pr + tid * 4) = o0;
  *(bf16x4*)(Pr + 1024 + tid * 4) = o1;
}

extern "C" void kernel_launch(void* const* d_in, const int* in_sizes, int n_in,
                              void* d_out, int out_size, void* d_ws,
                              size_t ws_size, hipStream_t stream) {
  const float* query = (const float*)d_in[0];
  const float* key_in = (const float*)d_in[1];
  const float* value = (const float*)d_in[2];
  const int* mask = (const int*)d_in[3];
  const float* Wq_w = (const float*)d_in[4];
  const float* Wq_b = (const float*)d_in[5];
  const float* Wk_w = (const float*)d_in[6];
  const float* Wk_b = (const float*)d_in[7];
  float* out = (float*)d_out;

  // workspace layout (224 MB), regions time-shared:
  //  [0,128MB):  qx(32) kx(32) wq(2) wk(2)  -> then S f32 (128)
  //  [128,192MB): qp(32) kp(32)             -> then P bf16 (64)
  //  [192,224MB): vt bf16 (32)
  const size_t MB = 1ull << 20;
  char* base = (char*)d_ws;
  bf16* qx = (bf16*)(base + 0 * MB);
  bf16* kx = (bf16*)(base + 32 * MB);
  bf16* wq = (bf16*)(base + 64 * MB);
  bf16* wk = (bf16*)(base + 66 * MB);
  float* S = (float*)(base + 0 * MB);
  bf16* qp = (bf16*)(base + 128 * MB);
  bf16* kp = (bf16*)(base + 160 * MB);
  bf16* P = (bf16*)(base + 128 * MB);
  bf16* vt = (bf16*)(base + 192 * MB);

  cvt_f32_bf16<<<8192, 256, 0, stream>>>(query, qx, 2097152);
  cvt_f32_bf16<<<8192, 256, 0, stream>>>(key_in, kx, 2097152);
  cvt_f32_bf16<<<512, 256, 0, stream>>>(Wq_w, wq, 131072);
  cvt_f32_bf16<<<512, 256, 0, stream>>>(Wk_w, wk, 131072);
  transpose_v<<<dim3(32, 64, 8), dim3(32, 8), 0, stream>>>(value, vt);

  // projections: q = query @ Wq^T + b, k = key @ Wk^T + b   (bf16 out)
  gemm_bt<0><<<dim3(8, 128, 1), 256, 0, stream>>>(
      qx, wq, qp, Wq_b, nullptr, 16384, 1024, 1024, 0, 0, 0);
  gemm_bt<0><<<dim3(8, 128, 1), 256, 0, stream>>>(
      kx, wk, kp, Wk_b, nullptr, 16384, 1024, 1024, 0, 0, 0);
  // scores: S = mask ? (q @ k^T)/32 : -1e9   (f32 out, batched)
  gemm_bt<1><<<dim3(16, 16, 8), 256, 0, stream>>>(
      qp, kp, S, nullptr, mask, 2048, 2048, 1024, 2048LL * 1024,
      2048LL * 1024, 2048LL * 2048);
  softmax_rows<<<16384, 256, 0, stream>>>(S, P);
  // out = P @ V  (via V^T, f32 out, batched)
  gemm_bt<2><<<dim3(8, 16, 8), 256, 0, stream>>>(
      P, vt, out, nullptr, nullptr, 2048, 1024, 2048, 2048LL * 2048,
      1024LL * 2048, 2048LL * 1024);
}

// Round 3
// 556.530 us; speedup vs baseline: 1.0864x; 1.0499x over previous
//
#include <hip/hip_runtime.h>

typedef __bf16 bf16;
typedef __bf16 bf16x8 __attribute__((ext_vector_type(8)));
typedef float f32x4 __attribute__((ext_vector_type(4)));
typedef float f32x16 __attribute__((ext_vector_type(16)));

// async global->LDS, 16B per lane; LDS dest is wave-uniform base + lane*16
__device__ __forceinline__ void gl_lds16(const bf16* g, bf16* l) {
  __builtin_amdgcn_global_load_lds(
      (__attribute__((address_space(1))) void*)g,
      (__attribute__((address_space(3))) void*)l, 16, 0, 0);
}

// ---------------- fp32 -> bf16 convert, 8 elems/thread ----------------
__global__ __launch_bounds__(256) void cvt_f32_bf16(
    const float* __restrict__ src, bf16* __restrict__ dst, int n8) {
  int i = blockIdx.x * 256 + threadIdx.x;
  if (i >= n8) return;
  const float4* s4 = (const float4*)src;
  float4 a = s4[2 * i], b = s4[2 * i + 1];
  bf16x8 o = {(bf16)a.x, (bf16)a.y, (bf16)a.z, (bf16)a.w,
              (bf16)b.x, (bf16)b.y, (bf16)b.z, (bf16)b.w};
  *(bf16x8*)(dst + (size_t)i * 8) = o;
}

// ------- V [2048,1024] f32 -> VT [1024,2048] bf16, per batch ----------
__global__ __launch_bounds__(256) void transpose_v(
    const float* __restrict__ V, bf16* __restrict__ VT) {
  int b = blockIdx.z;
  const float* Vb = V + (size_t)b * 2048 * 1024;
  bf16* Tb = VT + (size_t)b * 1024 * 2048;
  __shared__ float tile[32][33];  // +1 pad: conflict-free transposed read
  int tx = threadIdx.x, ty = threadIdx.y;
  int x = blockIdx.x * 32 + tx;
  int yb = blockIdx.y * 32;
#pragma unroll
  for (int j = 0; j < 4; j++)
    tile[ty + j * 8][tx] = Vb[(size_t)(yb + ty + j * 8) * 1024 + x];
  __syncthreads();
  int xo = yb + tx;
#pragma unroll
  for (int j = 0; j < 4; j++)
    Tb[(size_t)(blockIdx.x * 32 + ty + j * 8) * 2048 + xo] =
        (bf16)tile[tx][ty + j * 8];
}

// ---------------- shared B^T MFMA GEMM: C = A[M,K] * Bm[N,K]^T --------
// 32x32x16 MFMA (8 cyc / 32k FLOP vs 4.8 / 16k for 16x16x32): same LDS
// fragment traffic, ~half the MFMA-pipe + issue-slot demand per FLOP.
// LDS XOR-swizzled: row r granule g at slot g^(r&7); staging permutes the
// GLOBAL granule per lane (same 128B row -> same coalescing). Conflict-free
// (R1: 2.5e7 -> 0).
// MODE 0: C bf16 = acc + bias[col]            (projection)
// MODE 1: C bf16 = mask[col] ? acc/32 : -1e9  (QK^T scores)
// MODE 2: C f32  = acc                        (PV output)
template <int MODE>
__global__ __launch_bounds__(256) void gemm_bt(
    const bf16* __restrict__ A, const bf16* __restrict__ Bm,
    void* __restrict__ Cv, const float* __restrict__ bias,
    const int* __restrict__ mask, int M, int N, int K,
    long long sA, long long sB, long long sC) {
  const int b = blockIdx.z;
  const bf16* Ab = A + (long long)b * sA;
  const bf16* Bb = Bm + (long long)b * sB;
  const int m0 = blockIdx.y * 128, n0 = blockIdx.x * 128;
  __shared__ __align__(16) bf16 lA[128 * 64];
  __shared__ __align__(16) bf16 lB[128 * 64];
  const int tid = threadIdx.x, w = tid >> 6, lane = tid & 63;
  const int wm = (w >> 1) * 64, wn = (w & 1) * 64;  // 2x2 wave grid, 64x64/wave
  const int lrow = lane >> 3;                 // staging row within 8-row chunk
  const int gsw = (((lane & 7) ^ lrow) * 8);  // swizzled global granule

  f32x16 acc[2][2];
#pragma unroll
  for (int i = 0; i < 2; i++)
#pragma unroll
    for (int j = 0; j < 2; j++)
#pragma unroll
      for (int r = 0; r < 16; r++) acc[i][j][r] = 0.f;

  const bf16* Aq = Ab + (long long)m0 * K;
  const bf16* Bq = Bb + (long long)n0 * K;
  // 32x32x16 A/B frag: elem row = lane&31, k = (lane>>5)*8 + j
  const int fr = lane & 31;   // frag row (LDS row offset within wave tile)
  const int fh = lane >> 5;   // k-half selector
  const int key = lane & 7;   // swizzle key (== row&7 since tiles 8-aligned)

  for (int ks = 0; ks < K; ks += 64) {
    // stage 128x64 bf16 tiles of A and B; 8 rows (1 KiB) per wave-instr
#pragma unroll
    for (int i = 0; i < 4; i++) {
      int t = w * 4 + i;
      int r = t * 8 + lrow;
      gl_lds16(Aq + (long long)r * K + (ks + gsw), &lA[t * 512]);
      gl_lds16(Bq + (long long)r * K + (ks + gsw), &lB[t * 512]);
    }
    __syncthreads();  // implies s_waitcnt vmcnt(0): LDS writes visible
#pragma unroll
    for (int kc = 0; kc < 4; kc++) {
      const int g = ((kc * 2 + fh) ^ key) * 8;  // swizzled granule offset
      bf16x8 af[2], bfr[2];
#pragma unroll
      for (int mi = 0; mi < 2; mi++)
        af[mi] = *(const bf16x8*)&lA[(wm + mi * 32 + fr) * 64 + g];
#pragma unroll
      for (int ni = 0; ni < 2; ni++)
        bfr[ni] = *(const bf16x8*)&lB[(wn + ni * 32 + fr) * 64 + g];
#pragma unroll
      for (int mi = 0; mi < 2; mi++)
#pragma unroll
        for (int ni = 0; ni < 2; ni++)
          acc[mi][ni] = __builtin_amdgcn_mfma_f32_32x32x16_bf16(
              af[mi], bfr[ni], acc[mi][ni], 0, 0, 0);
    }
    __syncthreads();
  }

  // C/D layout (m74/m101-verified): col=lane&31,
  // row = (reg&3) + 8*(reg>>2) + 4*(lane>>5)
  const int ecol = lane & 31, er4 = (lane >> 5) * 4;
  if constexpr (MODE == 0) {
    bf16* C = (bf16*)Cv;
#pragma unroll
    for (int ni = 0; ni < 2; ni++) {
      int col = n0 + wn + ni * 32 + ecol;
      float bv = bias[col];
#pragma unroll
      for (int mi = 0; mi < 2; mi++)
#pragma unroll
        for (int r = 0; r < 16; r++) {
          int row = m0 + wm + mi * 32 + er4 + (r & 3) + 8 * (r >> 2);
          C[(long long)row * N + col] = (bf16)(acc[mi][ni][r] + bv);
        }
    }
  } else if constexpr (MODE == 1) {
    bf16* C = (bf16*)Cv + (long long)b * sC;
    const int* mb = mask + b * 2048;
#pragma unroll
    for (int ni = 0; ni < 2; ni++) {
      int col = n0 + wn + ni * 32 + ecol;
      bool keep = mb[col] != 0;
#pragma unroll
      for (int mi = 0; mi < 2; mi++)
#pragma unroll
        for (int r = 0; r < 16; r++) {
          int row = m0 + wm + mi * 32 + er4 + (r & 3) + 8 * (r >> 2);
          C[(long long)row * N + col] =
              keep ? (bf16)(acc[mi][ni][r] * 0.03125f) : (bf16)(-1e9f);
        }
    }
  } else {
    float* C = (float*)Cv + (long long)b * sC;
#pragma unroll
    for (int ni = 0; ni < 2; ni++) {
      int col = n0 + wn + ni * 32 + ecol;
#pragma unroll
      for (int mi = 0; mi < 2; mi++)
#pragma unroll
        for (int r = 0; r < 16; r++) {
          int row = m0 + wm + mi * 32 + er4 + (r & 3) + 8 * (r >> 2);
          C[(long long)row * N + col] = acc[mi][ni][r];
        }
    }
  }
}

// ------------- row softmax: S bf16 [.,2048] -> P bf16 -----------------
__global__ __launch_bounds__(256) void softmax_rows(
    const bf16* __restrict__ S, bf16* __restrict__ P) {
  long long row = blockIdx.x;
  const bf16x8* src = (const bf16x8*)(S + row * 2048);
  int tid = threadIdx.x, w = tid >> 6, lane = tid & 63;
  bf16x8 v = src[tid];
  float f[8];
#pragma unroll
  for (int i = 0; i < 8; i++) f[i] = (float)v[i];
  float m = f[0];
#pragma unroll
  for (int i = 1; i < 8; i++) m = fmaxf(m, f[i]);
#pragma unroll
  for (int off = 32; off; off >>= 1) m = fmaxf(m, __shfl_xor(m, off, 64));
  __shared__ float redm[4], reds[4];
  if (lane == 0) redm[w] = m;
  __syncthreads();
  m = fmaxf(fmaxf(redm[0], redm[1]), fmaxf(redm[2], redm[3]));
  float e[8], s = 0.f;
#pragma unroll
  for (int i = 0; i < 8; i++) {
    e[i] = __expf(f[i] - m);
    s += e[i];
  }
#pragma unroll
  for (int off = 32; off; off >>= 1) s += __shfl_xor(s, off, 64);
  if (lane == 0) reds[w] = s;
  __syncthreads();
  s = reds[0] + reds[1] + reds[2] + reds[3];
  float inv = 1.0f / s;
  bf16x8 o;
#pragma unroll
  for (int i = 0; i < 8; i++) o[i] = (bf16)(e[i] * inv);
  *(bf16x8*)(P + row * 2048 + tid * 8) = o;
}

extern "C" void kernel_launch(void* const* d_in, const int* in_sizes, int n_in,
                              void* d_out, int out_size, void* d_ws,
                              size_t ws_size, hipStream_t stream) {
  const float* query = (const float*)d_in[0];
  const float* key_in = (const float*)d_in[1];
  const float* value = (const float*)d_in[2];
  const int* mask = (const int*)d_in[3];
  const float* Wq_w = (const float*)d_in[4];
  const float* Wq_b = (const float*)d_in[5];
  const float* Wk_w = (const float*)d_in[6];
  const float* Wk_b = (const float*)d_in[7];
  float* out = (float*)d_out;

  // workspace layout (224 MB), regions time-shared:
  //  [0,128MB):  qx(32) kx(32) wq(2) wk(2)  -> then S bf16 (64)
  //  [128,192MB): qp(32) kp(32)             -> then P bf16 (64)
  //  [192,224MB): vt bf16 (32)
  const size_t MB = 1ull << 20;
  char* base = (char*)d_ws;
  bf16* qx = (bf16*)(base + 0 * MB);
  bf16* kx = (bf16*)(base + 32 * MB);
  bf16* wq = (bf16*)(base + 64 * MB);
  bf16* wk = (bf16*)(base + 66 * MB);
  bf16* S = (bf16*)(base + 0 * MB);
  bf16* qp = (bf16*)(base + 128 * MB);
  bf16* kp = (bf16*)(base + 160 * MB);
  bf16* P = (bf16*)(base + 128 * MB);
  bf16* vt = (bf16*)(base + 192 * MB);

  cvt_f32_bf16<<<8192, 256, 0, stream>>>(query, qx, 2097152);
  cvt_f32_bf16<<<8192, 256, 0, stream>>>(key_in, kx, 2097152);
  cvt_f32_bf16<<<512, 256, 0, stream>>>(Wq_w, wq, 131072);
  cvt_f32_bf16<<<512, 256, 0, stream>>>(Wk_w, wk, 131072);
  transpose_v<<<dim3(32, 64, 8), dim3(32, 8), 0, stream>>>(value, vt);

  // projections: q = query @ Wq^T + b, k = key @ Wk^T + b   (bf16 out)
  gemm_bt<0><<<dim3(8, 128, 1), 256, 0, stream>>>(
      qx, wq, qp, Wq_b, nullptr, 16384, 1024, 1024, 0, 0, 0);
  gemm_bt<0><<<dim3(8, 128, 1), 256, 0, stream>>>(
      kx, wk, kp, Wk_b, nullptr, 16384, 1024, 1024, 0, 0, 0);
  // scores: S = mask ? (q @ k^T)/32 : -1e9   (bf16 out, batched)
  gemm_bt<1><<<dim3(16, 16, 8), 256, 0, stream>>>(
      qp, kp, S, nullptr, mask, 2048, 2048, 1024, 2048LL * 1024,
      2048LL * 1024, 2048LL * 2048);
  softmax_rows<<<16384, 256, 0, stream>>>(S, P);
  // out = P @ V  (via V^T, f32 out, batched)
  gemm_bt<2><<<dim3(8, 16, 8), 256, 0, stream>>>(
      P, vt, out, nullptr, nullptr, 2048, 1024, 2048, 2048LL * 2048,
      1024LL * 2048, 2048LL * 1024);
}